// Round 4
// baseline (138.688 us; speedup 1.0000x reference)
//
#include <hip/hip_runtime.h>
#include <hip/hip_bf16.h>
#include <math.h>

#define B 4
#define T 128
#define C 512
#define NH 8
#define HS 64
#define BH (B*NH)   // 32

typedef __attribute__((ext_vector_type(8))) short bf16x8;
typedef __attribute__((ext_vector_type(4))) float f32x4;

__device__ __forceinline__ unsigned short bfc(float x) {
    return __builtin_bit_cast(unsigned short, __float2bfloat16(x));
}
__device__ __forceinline__ float b2f(unsigned short u) {
    unsigned int x = ((unsigned int)u) << 16;
    return __builtin_bit_cast(float, x);
}

// ---------------- prep: cvt X + transpose-cvt 4 weights + wcomb (2 slices) ----------------
__global__ __launch_bounds__(256) void prep_kernel(
    const float* __restrict__ X, const float* __restrict__ Wp0, const float* __restrict__ Wp1,
    const float* __restrict__ Wp2, const float* __restrict__ Wc,
    const float* __restrict__ Wv0, const float* __restrict__ Wv1,
    unsigned short* __restrict__ Xb, unsigned short* __restrict__ W0T, unsigned short* __restrict__ W1T,
    unsigned short* __restrict__ W2T, unsigned short* __restrict__ WcT,
    unsigned short* __restrict__ We0T, unsigned short* __restrict__ We1T)
{
    __shared__ float Ls[64][69];
    __shared__ float As[16][68];
    __shared__ float Bs[16][68];
    const int z = blockIdx.z;
    const int tid = threadIdx.x;
    if (z == 0) {
        const int r0 = blockIdx.y * 64, c0 = blockIdx.x * 64;
        #pragma unroll
        for (int it = 0; it < 2; ++it) {
            const int q = tid + it * 256;
            const int row = q >> 3, c8 = (q & 7) * 8;
            const float4 a = *(const float4*)&X[(size_t)(r0 + row) * 512 + c0 + c8];
            const float4 b = *(const float4*)&X[(size_t)(r0 + row) * 512 + c0 + c8 + 4];
            uint4 o;
            o.x = (unsigned int)bfc(a.x) | ((unsigned int)bfc(a.y) << 16);
            o.y = (unsigned int)bfc(a.z) | ((unsigned int)bfc(a.w) << 16);
            o.z = (unsigned int)bfc(b.x) | ((unsigned int)bfc(b.y) << 16);
            o.w = (unsigned int)bfc(b.z) | ((unsigned int)bfc(b.w) << 16);
            *(uint4*)&Xb[(size_t)(r0 + row) * 512 + c0 + c8] = o;
        }
        return;
    }
    if (z <= 4) {
        const int r0 = blockIdx.y * 64, c0 = blockIdx.x * 64;
        const float* W = (z == 1) ? Wp0 : (z == 2) ? Wp1 : (z == 3) ? Wp2 : Wc;
        unsigned short* WT = (z == 1) ? W0T : (z == 2) ? W1T : (z == 3) ? W2T : WcT;
        #pragma unroll
        for (int it = 0; it < 4; ++it) {
            const int q = tid + it * 256;
            const int row = q >> 4, c4 = (q & 15) * 4;
            const float4 v = *(const float4*)&W[(size_t)(r0 + row) * 512 + c0 + c4];
            Ls[row][c4 + 0] = v.x; Ls[row][c4 + 1] = v.y; Ls[row][c4 + 2] = v.z; Ls[row][c4 + 3] = v.w;
        }
        __syncthreads();
        #pragma unroll
        for (int it = 0; it < 2; ++it) {
            const int q = tid + it * 256;
            const int nrow = q >> 3, k8 = (q & 7) * 8;
            uint4 o;
            o.x = (unsigned int)bfc(Ls[k8 + 0][nrow]) | ((unsigned int)bfc(Ls[k8 + 1][nrow]) << 16);
            o.y = (unsigned int)bfc(Ls[k8 + 2][nrow]) | ((unsigned int)bfc(Ls[k8 + 3][nrow]) << 16);
            o.z = (unsigned int)bfc(Ls[k8 + 4][nrow]) | ((unsigned int)bfc(Ls[k8 + 5][nrow]) << 16);
            o.w = (unsigned int)bfc(Ls[k8 + 6][nrow]) | ((unsigned int)bfc(Ls[k8 + 7][nrow]) << 16);
            *(uint4*)&WT[(size_t)(c0 + nrow) * 512 + r0 + k8] = o;
        }
        return;
    }
    // z==5/6: We = Wp @ blockdiag(Wv), transposed bf16 out
    const float* A  = (z == 5) ? Wp1 : Wp2;
    const float* Wv = (z == 5) ? Wv0 : Wv1;
    unsigned short* O = (z == 5) ? We0T : We1T;
    const int h = blockIdx.x;
    const int m0 = blockIdx.y * 64;
    const int tx = tid & 15, ty = tid >> 4;
    const int arow = tid >> 2, acol = (tid & 3) * 4;
    const int brow = tid >> 4, bcol = (tid & 15) * 4;
    float acc[4][4] = {};
    for (int k0 = 0; k0 < 64; k0 += 16) {
        const float4 av = *(const float4*)&A[(size_t)(m0 + arow) * 512 + h * 64 + k0 + acol];
        const float4 bv = *(const float4*)&Wv[(size_t)(k0 + brow) * 64 + bcol];
        __syncthreads();
        As[acol + 0][arow] = av.x; As[acol + 1][arow] = av.y;
        As[acol + 2][arow] = av.z; As[acol + 3][arow] = av.w;
        *(float4*)&Bs[brow][bcol] = bv;
        __syncthreads();
        #pragma unroll
        for (int kk = 0; kk < 16; ++kk) {
            const float4 a4 = *(const float4*)&As[kk][ty * 4];
            const float4 b4 = *(const float4*)&Bs[kk][tx * 4];
            const float ar[4] = {a4.x, a4.y, a4.z, a4.w};
            const float br[4] = {b4.x, b4.y, b4.z, b4.w};
            #pragma unroll
            for (int r = 0; r < 4; ++r)
                #pragma unroll
                for (int c = 0; c < 4; ++c)
                    acc[r][c] = fmaf(ar[r], br[c], acc[r][c]);
        }
    }
    #pragma unroll
    for (int r = 0; r < 4; ++r)
        #pragma unroll
        for (int c = 0; c < 4; ++c)
            O[(size_t)(h * 64 + tx * 4 + c) * 512 + (m0 + ty * 4 + r)] = bfc(acc[r][c]);
}

// ---------------- bf16 MFMA projection GEMM; z==2 emits rowsums rr, never stores p2 ----------------
__global__ __launch_bounds__(256) void projmm_kernel(
    const unsigned short* __restrict__ Xb,
    const unsigned short* __restrict__ W0T, const unsigned short* __restrict__ W1T,
    const unsigned short* __restrict__ W2T,
    const unsigned short* __restrict__ We0T, const unsigned short* __restrict__ We1T,
    unsigned short* __restrict__ p0b, unsigned short* __restrict__ p1b,
    float* __restrict__ V0, unsigned short* __restrict__ V1T, float* __restrict__ rr)
{
    __shared__ __align__(16) unsigned short As[64][72];
    __shared__ __align__(16) unsigned short Bs[64][72];
    __shared__ float sRS[4][64];
    const int z = blockIdx.z;
    const unsigned short* WT = (z == 0) ? W0T : (z == 1) ? W1T : (z == 2) ? W2T : (z == 3) ? We0T : We1T;
    const int m0 = blockIdx.y * 64, n0 = blockIdx.x * 64;
    const int tid = threadIdx.x;
    const int w = tid >> 6, lane = tid & 63, quad = lane >> 4, l16 = lane & 15;
    f32x4 acc[4];
    #pragma unroll
    for (int mt = 0; mt < 4; ++mt) acc[mt] = (f32x4){0.f, 0.f, 0.f, 0.f};
    for (int k0 = 0; k0 < 512; k0 += 64) {
        __syncthreads();
        #pragma unroll
        for (int it = 0; it < 2; ++it) {
            const int q = tid + it * 256;
            const int row = q >> 3, c8 = (q & 7) * 8;
            *(uint4*)&As[row][c8] = *(const uint4*)&Xb[(size_t)(m0 + row) * 512 + k0 + c8];
            *(uint4*)&Bs[row][c8] = *(const uint4*)&WT[(size_t)(n0 + row) * 512 + k0 + c8];
        }
        __syncthreads();
        #pragma unroll
        for (int kt = 0; kt < 2; ++kt) {
            const bf16x8 b8 = *(const bf16x8*)&Bs[w * 16 + l16][kt * 32 + quad * 8];
            #pragma unroll
            for (int mt = 0; mt < 4; ++mt) {
                const bf16x8 a8 = *(const bf16x8*)&As[mt * 16 + l16][kt * 32 + quad * 8];
                acc[mt] = __builtin_amdgcn_mfma_f32_16x16x32_bf16(a8, b8, acc[mt], 0, 0, 0);
            }
        }
    }
    if (z == 2) {
        // rowsum epilogue: rr[b,h,t] = sum_d p2 (fp32 accs), never store p2
        #pragma unroll
        for (int mt = 0; mt < 4; ++mt)
            #pragma unroll
            for (int r = 0; r < 4; ++r) {
                float v = acc[mt][r];
                v += __shfl_xor(v, 1, 64); v += __shfl_xor(v, 2, 64);
                v += __shfl_xor(v, 4, 64); v += __shfl_xor(v, 8, 64);
                if (l16 == 0) sRS[w][mt * 16 + quad * 4 + r] = v;
            }
        __syncthreads();
        if (tid < 64) {
            const float s = sRS[0][tid] + sRS[1][tid] + sRS[2][tid] + sRS[3][tid];
            const int m = m0 + tid, b = m >> 7, tl = m & 127, h = n0 >> 6;
            rr[(b * NH + h) * T + tl] = s;
        }
        return;
    }
    const int n = n0 + w * 16 + l16;
    const int h = n >> 6, d = n & 63;
    #pragma unroll
    for (int mt = 0; mt < 4; ++mt) {
        #pragma unroll
        for (int r = 0; r < 4; ++r) {
            const int m = m0 + mt * 16 + quad * 4 + r;
            const int b = m >> 7, t = m & 127;
            const size_t hm = (size_t)(b * NH + h) * T + t;
            const float v = acc[mt][r];
            if (z == 0)      p0b[hm * HS + d] = bfc(v);
            else if (z == 1) p1b[hm * HS + d] = bfc(v);
            else if (z == 3) V0[hm * HS + d] = v;
            else             V1T[((size_t)(b * NH + h) * HS + d) * T + t] = bfc(v);
        }
    }
}

// ---------------- main attention: one block per (bh, pair (i1=p, i2=127-p)) ----------------
__global__ __launch_bounds__(256) void attn_kernel(
    const unsigned short* __restrict__ p0b, const unsigned short* __restrict__ p1b,
    const float* __restrict__ rr, const float* __restrict__ V0g,
    const unsigned short* __restrict__ V1Tg, unsigned short* __restrict__ Yb)
{
    __shared__ __align__(16) unsigned short sE[128 * 128];  // 32 KB, xor-swizzled 16B chunks
    __shared__ float sS[2][128];
    __shared__ float sP0[2][64];
    __shared__ float srr[128];
    __shared__ float spx[128];
    __shared__ float spn[128];
    __shared__ float sM[8];
    __shared__ float sZ[4];

    const int blk = blockIdx.x;
    const int bh = blk & (BH - 1);
    const int p = blk >> 5;                 // 0..63
    const int i1 = p, i2 = 127 - p;
    const int tid = threadIdx.x;
    const int w = tid >> 6;
    const int lane = tid & 63;
    const int quad = lane >> 4;
    const int l16 = lane & 15;

    // stage r and the two p0 rows
    if (tid < 128) {
        srr[tid] = rr[bh * T + tid];
        const int si = tid >> 6, dd = tid & 63;
        sP0[si][dd] = b2f(p0b[((size_t)bh * T + (si ? i2 : i1)) * HS + dd]);
    }
    // V1 B-fragments in registers
    uint4 v1r[4];
    {
        const unsigned short* src = V1Tg + ((size_t)bh * HS + w * 16 + l16) * T;
        #pragma unroll
        for (int kt = 0; kt < 4; ++kt) v1r[kt] = *(const uint4*)&src[kt * 32 + quad * 8];
    }
    __syncthreads();                                       // bar1

    const float rv0 = srr[2 * lane], rv1 = srr[2 * lane + 1];

    // S dots: waves 0,1 -> i1; waves 2,3 -> i2 (fp32)
    const int ii = tid >> 7;
    const int j = tid & 127;
    const int i_me = ii ? i2 : i1;
    float Sv;
    {
        const unsigned short* prow = p1b + ((size_t)bh * T + j) * HS;
        float s = 0.f;
        #pragma unroll
        for (int c = 0; c < 64; c += 8) {
            const uint4 u = *(const uint4*)&prow[c];
            s = fmaf(b2f((unsigned short)(u.x & 0xffff)), sP0[ii][c + 0], s);
            s = fmaf(b2f((unsigned short)(u.x >> 16)),    sP0[ii][c + 1], s);
            s = fmaf(b2f((unsigned short)(u.y & 0xffff)), sP0[ii][c + 2], s);
            s = fmaf(b2f((unsigned short)(u.y >> 16)),    sP0[ii][c + 3], s);
            s = fmaf(b2f((unsigned short)(u.z & 0xffff)), sP0[ii][c + 4], s);
            s = fmaf(b2f((unsigned short)(u.z >> 16)),    sP0[ii][c + 5], s);
            s = fmaf(b2f((unsigned short)(u.w & 0xffff)), sP0[ii][c + 6], s);
            s = fmaf(b2f((unsigned short)(u.w >> 16)),    sP0[ii][c + 7], s);
        }
        Sv = s * 0.125f;
        sS[ii][j] = Sv;
    }

    // prefix max/min scan of r over 128 (waves 0,1)
    float px = 0.f, pn = 0.f;
    if (tid < 128) {
        px = srr[tid]; pn = px;
        #pragma unroll
        for (int off = 1; off <= 32; off <<= 1) {
            const float ox = __shfl(px, lane - off, 64);
            const float on = __shfl(pn, lane - off, 64);
            if (lane >= off) { px = fmaxf(px, ox); pn = fminf(pn, on); }
        }
        if (tid == 63) { sM[6] = px; sM[7] = pn; }
    }
    __syncthreads();                                       // bar2
    if (tid >= 64 && tid < 128) { px = fmaxf(px, sM[6]); pn = fminf(pn, sM[7]); }
    if (tid < 128) { spx[tid] = px; spn[tid] = pn; }
    __syncthreads();                                       // bar3

    // exact max per i
    float cand = -INFINITY;
    if (j <= i_me) cand = (Sv >= 0.f) ? Sv * spx[j] : Sv * spn[j];
    #pragma unroll
    for (int off = 32; off; off >>= 1) cand = fmaxf(cand, __shfl_xor(cand, off, 64));
    if (lane == 0) sM[w] = cand;
    __syncthreads();                                       // bar4
    const float m1 = fmaxf(sM[0], sM[1]);
    const float m2 = fmaxf(sM[2], sM[3]);

    const float L2E = 1.4426950408889634f;
    const int chunkb = lane >> 2;
    const int inoff = (lane & 3) << 2;
    const int k0 = 2 * lane, k1 = k0 + 1;

    // ---- phase i2 ----
    const int mtmax2 = i2 >> 4;                            // 4..7
    const int jmax2 = (mtmax2 << 4) + 15;
    float bexp = -m2 * L2E;
    float zacc = 0.f;
    for (int jj = w; jj <= jmax2; jj += 4) {
        unsigned int pk = 0;
        if (jj <= i2) {
            const float aL = sS[1][jj] * L2E;
            float e0 = __builtin_amdgcn_exp2f(fmaf(aL, rv0, bexp));
            float e1 = __builtin_amdgcn_exp2f(fmaf(aL, rv1, bexp));
            e0 = (k0 <= jj) ? e0 : 0.f;
            e1 = (k1 <= jj) ? e1 : 0.f;
            zacc += e0 + e1;
            pk = (unsigned int)bfc(e0) | ((unsigned int)bfc(e1) << 16);
        }
        const int swz = chunkb ^ (jj & 15);
        *(unsigned int*)((char*)sE + (jj << 8) + (swz << 4) + inoff) = pk;
    }
    #pragma unroll
    for (int off = 32; off; off >>= 1) zacc += __shfl_xor(zacc, off, 64);
    if (lane == 0) sZ[w] = zacc;
    __syncthreads();                                       // bar5
    const float Z2 = sZ[0] + sZ[1] + sZ[2] + sZ[3];

    f32x4 acc2[8];
    #pragma unroll
    for (int mt = 0; mt < 8; ++mt) acc2[mt] = (f32x4){0.f, 0.f, 0.f, 0.f};
    #pragma unroll
    for (int mt = 0; mt < 8; ++mt) {
        if (mt <= mtmax2) {
            #pragma unroll
            for (int kt = 0; kt <= (mt >> 1); ++kt) {
                const int swz = (4 * kt + quad) ^ l16;
                const bf16x8 a8 = *(const bf16x8*)((char*)sE + (((mt << 4) + l16) << 8) + (swz << 4));
                acc2[mt] = __builtin_amdgcn_mfma_f32_16x16x32_bf16(
                    a8, __builtin_bit_cast(bf16x8, v1r[kt]), acc2[mt], 0, 0, 0);
            }
        }
    }
    __syncthreads();                                       // bar6 (sE reads done)

    // ---- phase i1 ----
    const int mtmax1 = i1 >> 4;                            // 0..3
    const int jmax1 = (mtmax1 << 4) + 15;
    bexp = -m1 * L2E;
    zacc = 0.f;
    for (int jj = w; jj <= jmax1; jj += 4) {
        unsigned int pk = 0;
        if (jj <= i1) {
            const float aL = sS[0][jj] * L2E;
            float e0 = __builtin_amdgcn_exp2f(fmaf(aL, rv0, bexp));
            float e1 = __builtin_amdgcn_exp2f(fmaf(aL, rv1, bexp));
            e0 = (k0 <= jj) ? e0 : 0.f;
            e1 = (k1 <= jj) ? e1 : 0.f;
            zacc += e0 + e1;
            pk = (unsigned int)bfc(e0) | ((unsigned int)bfc(e1) << 16);
        }
        const int swz = chunkb ^ (jj & 15);
        *(unsigned int*)((char*)sE + (jj << 8) + (swz << 4) + inoff) = pk;
    }
    #pragma unroll
    for (int off = 32; off; off >>= 1) zacc += __shfl_xor(zacc, off, 64);
    if (lane == 0) sZ[w] = zacc;
    __syncthreads();                                       // bar7
    const float Z1 = sZ[0] + sZ[1] + sZ[2] + sZ[3];

    f32x4 acc1[4];
    #pragma unroll
    for (int mt = 0; mt < 4; ++mt) acc1[mt] = (f32x4){0.f, 0.f, 0.f, 0.f};
    #pragma unroll
    for (int mt = 0; mt < 4; ++mt) {
        if (mt <= mtmax1) {
            #pragma unroll
            for (int kt = 0; kt <= (mt >> 1); ++kt) {
                const int swz = (4 * kt + quad) ^ l16;
                const bf16x8 a8 = *(const bf16x8*)((char*)sE + (((mt << 4) + l16) << 8) + (swz << 4));
                acc1[mt] = __builtin_amdgcn_mfma_f32_16x16x32_bf16(
                    a8, __builtin_bit_cast(bf16x8, v1r[kt]), acc1[mt], 0, 0, 0);
            }
        }
    }

    // epilogues (VMEM overlaps; single drain at end)
    const float* v0b = V0g + (size_t)bh * T * HS;
    const int d = (w << 4) + l16;
    const int bb = bh >> 3, hh = bh & 7;
    float part2 = 0.f;
    #pragma unroll
    for (int mt = 0; mt < 8; ++mt) {
        if (mt <= mtmax2) {
            #pragma unroll
            for (int r = 0; r < 4; ++r) {
                const int jr = (mt << 4) + (quad << 2) + r;
                if (jr <= i2) part2 = fmaf(v0b[jr * HS + d], acc2[mt][r], part2);
            }
        }
    }
    part2 += __shfl_xor(part2, 16, 64);
    part2 += __shfl_xor(part2, 32, 64);
    float part1 = 0.f;
    #pragma unroll
    for (int mt = 0; mt < 4; ++mt) {
        if (mt <= mtmax1) {
            #pragma unroll
            for (int r = 0; r < 4; ++r) {
                const int jr = (mt << 4) + (quad << 2) + r;
                if (jr <= i1) part1 = fmaf(v0b[jr * HS + d], acc1[mt][r], part1);
            }
        }
    }
    part1 += __shfl_xor(part1, 16, 64);
    part1 += __shfl_xor(part1, 32, 64);
    if (lane < 16) {
        Yb[((size_t)(bb * T + i2) * C) + hh * HS + d] = bfc(part2 / Z2);
        Yb[((size_t)(bb * T + i1) * C) + hh * HS + d] = bfc(part1 / Z1);
    }
}

// ---------------- OUT = Yb @ Wc (bf16 MFMA, fp32 out) ----------------
__global__ __launch_bounds__(256) void outmm_kernel(
    const unsigned short* __restrict__ Ab, const unsigned short* __restrict__ WT,
    float* __restrict__ OUT)
{
    __shared__ __align__(16) unsigned short As[64][72];
    __shared__ __align__(16) unsigned short Bs[64][72];
    const int m0 = blockIdx.y * 64, n0 = blockIdx.x * 64;
    const int tid = threadIdx.x;
    const int w = tid >> 6, lane = tid & 63, quad = lane >> 4, l16 = lane & 15;
    f32x4 acc[4];
    #pragma unroll
    for (int mt = 0; mt < 4; ++mt) acc[mt] = (f32x4){0.f, 0.f, 0.f, 0.f};
    for (int k0 = 0; k0 < 512; k0 += 64) {
        __syncthreads();
        #pragma unroll
        for (int it = 0; it < 2; ++it) {
            const int q = tid + it * 256;
            const int row = q >> 3, c8 = (q & 7) * 8;
            *(uint4*)&As[row][c8] = *(const uint4*)&Ab[(size_t)(m0 + row) * 512 + k0 + c8];
            *(uint4*)&Bs[row][c8] = *(const uint4*)&WT[(size_t)(n0 + row) * 512 + k0 + c8];
        }
        __syncthreads();
        #pragma unroll
        for (int kt = 0; kt < 2; ++kt) {
            const bf16x8 b8 = *(const bf16x8*)&Bs[w * 16 + l16][kt * 32 + quad * 8];
            #pragma unroll
            for (int mt = 0; mt < 4; ++mt) {
                const bf16x8 a8 = *(const bf16x8*)&As[mt * 16 + l16][kt * 32 + quad * 8];
                acc[mt] = __builtin_amdgcn_mfma_f32_16x16x32_bf16(a8, b8, acc[mt], 0, 0, 0);
            }
        }
    }
    const int n = n0 + w * 16 + l16;
    #pragma unroll
    for (int mt = 0; mt < 4; ++mt)
        #pragma unroll
        for (int r = 0; r < 4; ++r) {
            const int mrow = m0 + mt * 16 + quad * 4 + r;
            OUT[(size_t)mrow * 512 + n] = acc[mt][r];
        }
}

extern "C" void kernel_launch(void* const* d_in, const int* in_sizes, int n_in,
                              void* d_out, int out_size, void* d_ws, size_t ws_size,
                              hipStream_t stream)
{
    const float* x   = (const float*)d_in[0];
    const float* Wp0 = (const float*)d_in[1];
    const float* Wp1 = (const float*)d_in[2];
    const float* Wp2 = (const float*)d_in[3];
    const float* Wv0 = (const float*)d_in[4];
    const float* Wv1 = (const float*)d_in[5];
    const float* Wc  = (const float*)d_in[6];
    float* out = (float*)d_out;

    char* w8 = (char*)d_ws;
    const size_t HB = 512 * 1024;
    unsigned short* Xb   = (unsigned short*)(w8 + 0 * HB);
    unsigned short* W0T  = (unsigned short*)(w8 + 1 * HB);
    unsigned short* W1T  = (unsigned short*)(w8 + 2 * HB);
    unsigned short* W2T  = (unsigned short*)(w8 + 3 * HB);
    unsigned short* WcT  = (unsigned short*)(w8 + 4 * HB);
    unsigned short* We0T = (unsigned short*)(w8 + 5 * HB);
    unsigned short* We1T = (unsigned short*)(w8 + 6 * HB);
    unsigned short* p0b  = (unsigned short*)(w8 + 7 * HB);
    unsigned short* p1b  = (unsigned short*)(w8 + 8 * HB);
    float*          V0   = (float*)        (w8 + 9 * HB);   // 1 MB
    unsigned short* V1T  = (unsigned short*)(w8 + 11 * HB);
    unsigned short* Yb   = (unsigned short*)(w8 + 12 * HB);
    float*          rr   = (float*)        (w8 + 13 * HB);

    prep_kernel  <<<dim3(8, 8, 7), 256, 0, stream>>>(x, Wp0, Wp1, Wp2, Wc, Wv0, Wv1,
                                                     Xb, W0T, W1T, W2T, WcT, We0T, We1T);
    projmm_kernel<<<dim3(8, 8, 5), 256, 0, stream>>>(Xb, W0T, W1T, W2T, We0T, We1T,
                                                     p0b, p1b, V0, V1T, rr);
    attn_kernel  <<<dim3(BH * 64), 256, 0, stream>>>(p0b, p1b, rr, V0, V1T, Yb);
    outmm_kernel <<<dim3(8, 8), 256, 0, stream>>>(Yb, WcT, out);
}